// Round 10
// baseline (95.927 us; speedup 1.0000x reference)
//
#include <hip/hip_runtime.h>
#include <hip/hip_bf16.h>
#include <stdint.h>

// MinGRU: B=8, S=4096, I=512, H=512 (fp32 in/out)
// R9: gemm switched to mfma_f32_32x32x16_bf16 (wave = 2x2 tiles of 32x32 per
//     mat; 16 MFMA/wave/K-step instead of 32; ceiling 2075->2382 TF) and
//     single-barrier K-loop (wait vmcnt(6) -> barrier -> stage(kt+2) ->
//     ds_read -> MFMA; 16 barriers instead of 32). 3 x 24 KiB buffers,
//     XCD-chunked grid. Other kernels unchanged.

typedef __attribute__((ext_vector_type(8)))  short short8;   // 8 bf16
typedef __attribute__((ext_vector_type(16))) float f32x16;

#define AS1 __attribute__((address_space(1)))
#define AS3 __attribute__((address_space(3)))

__device__ inline void gload_lds16(const void* g, void* l) {
  __builtin_amdgcn_global_load_lds((AS1 uint32_t*)(g), (AS3 uint32_t*)(l), 16, 0, 0);
}

__device__ inline ushort f2bf(float f) {
  union { __hip_bfloat16 h; ushort u; } v;
  v.h = __float2bfloat16(f);
  return v.u;
}

// ---------------- K0: fp32 -> bf16 (x, W_z, W_h in one launch) ----------------
__global__ void cvt_all(const float* __restrict__ x,
                        const float* __restrict__ wz,
                        const float* __restrict__ wh,
                        ushort* __restrict__ xb,
                        ushort* __restrict__ wzb,
                        ushort* __restrict__ whb) {
  int i = blockIdx.x * 256 + threadIdx.x;
  for (; i < 4325376; i += 2048 * 256) {
    const float* s; ushort* d; int j;
    if (i < 4194304)      { s = x;  d = xb;  j = i; }
    else if (i < 4259840) { s = wz; d = wzb; j = i - 4194304; }
    else                  { s = wh; d = whb; j = i - 4259840; }
    float4 v = reinterpret_cast<const float4*>(s)[j];
    ushort4 o = make_ushort4(f2bf(v.x), f2bf(v.y), f2bf(v.z), f2bf(v.w));
    reinterpret_cast<ushort4*>(d)[j] = o;
  }
}

// ---------------- K1: GEMM (32x32x16 MFMA) + gate + chunk summaries --------
// grid 1024 (XCD-chunked): tile=(bid&7)*128+(bid>>3); bx=tile>>2, by=tile&3.
// 4 waves 2x2: wave = 64 rows x 64 cols x {z,h~} = 2x2 tiles of 32x32/mat.
// LDS: 3 x (A 8K | Bz 8K | Bh 8K) = 72 KiB, BK=32, 16 K-steps.
// Single barrier/K-step: wait vmcnt(6); barrier; stage(kt+2); ds_read; MFMA.
// Rows 64B, 16B-slot swizzle slot ^= (row>>1)&3.
__global__ __launch_bounds__(256, 2) void gemm_gate(
    const ushort* __restrict__ xb,   // [32768,512] bf16
    const ushort* __restrict__ wzb,  // [512,512] bf16
    const ushort* __restrict__ whb,  // [512,512] bf16
    const float* __restrict__ b_z,
    const float* __restrict__ b_h,
    uint* __restrict__ ab,           // [32768,512] packed (a,b) bf16
    float2* __restrict__ ABc)        // [8,512,128] chunk summaries (b,h,c)
{
  __shared__ __align__(16) char smem[73728];
  // buffer (24 KiB): A [0,8192) 128x32 bf16, Bz [8192,16384), Bh [16384,24576)

  const int t   = threadIdx.x;
  const int w   = t >> 6;
  const int l   = t & 63;
  const int c32 = l & 31;       // MFMA row (A) / col (B,C)
  const int hi  = l >> 5;       // k-group / C row offset
  const int wm = w >> 1, wn = w & 1;
  const int bid  = blockIdx.x;
  const int tile = (bid & 7) * 128 + (bid >> 3);   // bijective (1024 % 8 == 0)
  const int bx = tile >> 2;
  const int by = tile & 3;
  const int m0 = bx * 128;
  const int n0 = by * 128;

  const int srow = t >> 2;     // staging: 0..63 rows per issue
  const int ssl  = t & 3;      // 16B slot within 64B row

  f32x16 accz[2][2], acch[2][2];
  #pragma unroll
  for (int tm = 0; tm < 2; ++tm)
    #pragma unroll
    for (int tn = 0; tn < 2; ++tn) {
      accz[tm][tn] = (f32x16)(0.f);
      acch[tm][tn] = (f32x16)(0.f);
    }

  // Exactly 6 gload_lds per stage; no other vmcnt ops in the K-loop.
  auto stage = [&](int sel, int kt) {
    char* base = smem + sel * 24576;
    const int k0 = kt * 32;
    #pragma unroll
    for (int j = 0; j < 2; ++j) {
      int row = j * 64 + srow;
      int gs  = ssl ^ ((row >> 1) & 3);
      gload_lds16(xb + (size_t)(m0 + row) * 512 + k0 + gs * 8,
                  base + j * 4096 + w * 1024);
      gload_lds16(wzb + (size_t)(n0 + row) * 512 + k0 + gs * 8,
                  base + 8192 + j * 4096 + w * 1024);
      gload_lds16(whb + (size_t)(n0 + row) * 512 + k0 + gs * 8,
                  base + 16384 + j * 4096 + w * 1024);
    }
  };

  stage(0, 0);
  stage(1, 1);                              // 12 outstanding

  #pragma unroll
  for (int kt = 0; kt < 16; ++kt) {
    const int sel = kt % 3;
    if (kt < 15) {
      asm volatile("s_waitcnt vmcnt(6)" ::: "memory");   // tile kt landed
    } else {
      asm volatile("s_waitcnt vmcnt(0)" ::: "memory");
    }
    __builtin_amdgcn_s_barrier();           // all waves' tile-kt data landed;
                                            // also fences buf[(kt+2)%3] reuse
    if (kt < 14) stage((kt + 2) % 3, kt + 2);

    const char* base = smem + sel * 24576;
    short8 af[2][2], bfz[2][2], bfh[2][2];  // [tile][ks]
    #pragma unroll
    for (int tm = 0; tm < 2; ++tm) {
      int row = wm * 64 + tm * 32 + c32;
      int rsw = (row >> 1) & 3;
      #pragma unroll
      for (int ks = 0; ks < 2; ++ks)
        af[tm][ks] = *(const short8*)(base + row * 64 + (((ks * 2 + hi) ^ rsw) << 4));
    }
    #pragma unroll
    for (int tn = 0; tn < 2; ++tn) {
      int row = wn * 64 + tn * 32 + c32;
      int rsw = (row >> 1) & 3;
      #pragma unroll
      for (int ks = 0; ks < 2; ++ks) {
        int so = (((ks * 2 + hi) ^ rsw) << 4);
        bfz[tn][ks] = *(const short8*)(base + 8192  + row * 64 + so);
        bfh[tn][ks] = *(const short8*)(base + 16384 + row * 64 + so);
      }
    }
    __builtin_amdgcn_s_setprio(1);
    #pragma unroll
    for (int tm = 0; tm < 2; ++tm)
      #pragma unroll
      for (int tn = 0; tn < 2; ++tn) {
        accz[tm][tn] = __builtin_amdgcn_mfma_f32_32x32x16_bf16(af[tm][0], bfz[tn][0], accz[tm][tn], 0, 0, 0);
        accz[tm][tn] = __builtin_amdgcn_mfma_f32_32x32x16_bf16(af[tm][1], bfz[tn][1], accz[tm][tn], 0, 0, 0);
        acch[tm][tn] = __builtin_amdgcn_mfma_f32_32x32x16_bf16(af[tm][0], bfh[tn][0], acch[tm][tn], 0, 0, 0);
        acch[tm][tn] = __builtin_amdgcn_mfma_f32_32x32x16_bf16(af[tm][1], bfh[tn][1], acch[tm][tn], 0, 0, 0);
      }
    __builtin_amdgcn_s_setprio(0);
  }

  // ---- gate epilogue + chunk summaries ----
  // C layout (m74/m101): col = lane&31, row = (reg&3) + 8*(reg>>2) + 4*hi.
  // Each 32x32 tile (tm) spans exactly one time-chunk of 32 rows.
  const int bidx = bx >> 5;                      // batch
  #pragma unroll
  for (int tm = 0; tm < 2; ++tm) {
    #pragma unroll
    for (int tn = 0; tn < 2; ++tn) {
      const int col = n0 + wn * 64 + tn * 32 + c32;
      const float bzn = b_z[col];
      const float bhn = b_h[col];
      float segA[4], segB[4];
      #pragma unroll
      for (int q = 0; q < 4; ++q) {
        float A = 1.f, Bv = 0.f;
        #pragma unroll
        for (int j = 0; j < 4; ++j) {
          const int reg  = q * 4 + j;
          const int rloc = j + 8 * q + 4 * hi;
          float uz = accz[tm][tn][reg] + bzn;
          float uh = acch[tm][tn][reg] + bhn;
          float z  = 1.f / (1.f + __expf(-uz));
          float a  = 1.f - z;
          float bb = z * uh;
          size_t grow = (size_t)(m0 + wm * 64 + tm * 32 + rloc);
          ab[grow * 512 + col] = (uint)f2bf(a) | ((uint)f2bf(bb) << 16);
          A  = a * A;
          Bv = a * Bv + bb;          // j ascending = time ascending
        }
        segA[q] = A;
        segB[q] = Bv;
      }
      // partner (lane ^ 32) holds the other 4-row half of each 8-row group
      float FA = 1.f, FB = 0.f;
      #pragma unroll
      for (int q = 0; q < 4; ++q) {
        float pA = __shfl_xor(segA[q], 32);
        float pB = __shfl_xor(segB[q], 32);
        float fA = hi ? pA : segA[q];     // rows 8q+0..3
        float fB = hi ? pB : segB[q];
        float sA = hi ? segA[q] : pA;     // rows 8q+4..7
        float sB = hi ? segB[q] : pB;
        FB = fA * FB + fB; FA = fA * FA;
        FB = sA * FB + sB; FA = sA * FA;
      }
      if (hi == 0) {
        int c = (bx & 31) * 4 + wm * 2 + tm;     // chunk within batch
        ABc[((size_t)bidx * 512 + col) * 128 + c] = make_float2(FA, FB);
      }
    }
  }
}

// ---------------- K3: wave-parallel scan over chunk summaries ----------------
__global__ __launch_bounds__(256) void chunk_scan(
    const float2* __restrict__ ABc,   // [8,512,128]
    const float* __restrict__ h0,
    float* __restrict__ Hinit)        // [8,128,512]
{
  __shared__ float sm[128][4];
  const int w = threadIdx.x >> 6, l = threadIdx.x & 63;
  const int b   = blockIdx.x >> 7;
  const int h0g = (blockIdx.x & 127) * 4;
  const int h   = h0g + w;

  const float2* base = ABc + ((size_t)b * 512 + h) * 128;
  float2 s1 = base[l];
  float2 s2 = base[64 + l];

  float A1 = s1.x, B1 = s1.y;
  #pragma unroll
  for (int d = 1; d < 64; d <<= 1) {
    float uA = __shfl_up(A1, d);
    float uB = __shfl_up(B1, d);
    if (l >= d) { B1 = A1 * uB + B1; A1 = A1 * uA; }
  }
  float A2 = s2.x, B2 = s2.y;
  #pragma unroll
  for (int d = 1; d < 64; d <<= 1) {
    float uA = __shfl_up(A2, d);
    float uB = __shfl_up(B2, d);
    if (l >= d) { B2 = A2 * uB + B2; A2 = A2 * uA; }
  }
  float PA = __shfl(A1, 63), PB = __shfl(B1, 63);   // prefix of chunks 0..63
  float FA = A2 * PA;
  float FB = A2 * PB + B2;

  float e1A = __shfl_up(A1, 1), e1B = __shfl_up(B1, 1);
  if (l == 0) { e1A = 1.f; e1B = 0.f; }
  float e2A = __shfl_up(FA, 1), e2B = __shfl_up(FB, 1);
  if (l == 0) { e2A = PA; e2B = PB; }

  float h0v = h0[b * 512 + h];
  sm[l][w]      = e1A * h0v + e1B;
  sm[64 + l][w] = e2A * h0v + e2B;
  __syncthreads();

  const int tt = threadIdx.x;
  if (tt < 128) {
    float4 v = *(const float4*)sm[tt];
    *(float4*)(Hinit + ((size_t)b * 128 + tt) * 512 + h0g) = v;
  }
}

// ---------------- K4: replay each chunk from Hinit, write out ----------------
__global__ __launch_bounds__(256) void scan_write(
    const uint* __restrict__ ab,
    const float* __restrict__ Hinit,
    float* __restrict__ out)
{
  int tid = blockIdx.x * 256 + threadIdx.x;   // 131072
  int cg = tid & 127;            // h-group: h = cg*4 ..
  int c  = (tid >> 7) & 127;
  int b  = tid >> 14;
  const uint4* p = reinterpret_cast<const uint4*>(ab + ((size_t)(b * 4096 + c * 32)) * 512) + cg;
  float4 hv = *reinterpret_cast<const float4*>(Hinit + ((size_t)b * 128 + c) * 512 + cg * 4);
  float4* po = reinterpret_cast<float4*>(out + ((size_t)(b * 4096 + c * 32)) * 512) + cg;
  #pragma unroll 4
  for (int t = 0; t < 32; ++t) {
    uint4 u = p[(size_t)t * 128];
    hv.x = __uint_as_float(u.x << 16) * hv.x + __uint_as_float(u.x & 0xffff0000u);
    hv.y = __uint_as_float(u.y << 16) * hv.y + __uint_as_float(u.y & 0xffff0000u);
    hv.z = __uint_as_float(u.z << 16) * hv.z + __uint_as_float(u.z & 0xffff0000u);
    hv.w = __uint_as_float(u.w << 16) * hv.w + __uint_as_float(u.w & 0xffff0000u);
    po[(size_t)t * 128] = hv;
  }
}

extern "C" void kernel_launch(void* const* d_in, const int* in_sizes, int n_in,
                              void* d_out, int out_size, void* d_ws, size_t ws_size,
                              hipStream_t stream) {
  const float* x   = (const float*)d_in[0];
  const float* h0  = (const float*)d_in[1];
  const float* W_z = (const float*)d_in[2];
  const float* b_z = (const float*)d_in[3];
  const float* W_h = (const float*)d_in[4];
  const float* b_h = (const float*)d_in[5];
  float* out = (float*)d_out;

  char* ws = (char*)d_ws;
  ushort* xb    = (ushort*)(ws);                  // 33,554,432 B
  ushort* wzb   = (ushort*)(ws + 33554432);       //    524,288 B
  ushort* whb   = (ushort*)(ws + 34078720);       //    524,288 B
  uint*   ab    = (uint*)  (ws + 34603008);       // 67,108,864 B
  float2* ABc   = (float2*)(ws + 101711872);      //  4,194,304 B  [8,512,128]
  float*  Hinit = (float*) (ws + 105906176);      //  2,097,152 B  [8,128,512]

  cvt_all<<<2048, 256, 0, stream>>>(x, W_z, W_h, xb, wzb, whb);
  gemm_gate<<<1024, 256, 0, stream>>>(xb, wzb, whb, b_z, b_h, ab, ABc);
  chunk_scan<<<1024, 256, 0, stream>>>(ABc, h0, Hinit);
  scan_write<<<512, 256, 0, stream>>>(ab, Hinit, out);
}

// Round 11
// 91.273 us; speedup vs baseline: 1.0510x; 1.0510x over previous
//
#include <hip/hip_runtime.h>
#include <hip/hip_bf16.h>
#include <stdint.h>

// MinGRU: B=8, S=4096, I=512, H=512 (fp32 in/out)
// R10: gemm -> m201-style 8-phase 256x256x64 template (the proven 1563 TF
//      structure). Weights packed as Wcat[1024,512] with 32-row z/h
//      interleave so one standard GEMM computes both mats and the gate
//      fuses in-lane. 8 waves (512 thr), LDS 128K (2 dbuf x A32K+B32K),
//      counted vmcnt(4) at phases 4/8 only, raw barriers, setprio.
//      chunk_scan / scan_write unchanged.

typedef __attribute__((ext_vector_type(8))) short short8;   // 8 bf16
typedef __attribute__((ext_vector_type(4))) float f32x4;

#define AS1 __attribute__((address_space(1)))
#define AS3 __attribute__((address_space(3)))

__device__ inline void gload_lds16(const void* g, void* l) {
  __builtin_amdgcn_global_load_lds((AS1 uint32_t*)(g), (AS3 uint32_t*)(l), 16, 0, 0);
}

__device__ inline ushort f2bf(float f) {
  union { __hip_bfloat16 h; ushort u; } v;
  v.h = __float2bfloat16(f);
  return v.u;
}

// ---------------- K0: fp32 -> bf16; also builds interleaved Wcat ------------
// Wcat[1024,512]: row r: g=r>>6, q=r&63; q<32 -> Wz[g*32+q], else Wh[g*32+q-32].
__global__ void cvt_all(const float* __restrict__ x,
                        const float* __restrict__ wz,
                        const float* __restrict__ wh,
                        ushort* __restrict__ xb,
                        ushort* __restrict__ wcat) {
  int i = blockIdx.x * 256 + threadIdx.x;
  for (; i < 4325376; i += 2048 * 256) {
    const float* s; ushort* d; int j;
    if (i < 4194304) {
      s = x; d = xb; j = i;
      float4 v = reinterpret_cast<const float4*>(s)[j];
      reinterpret_cast<ushort4*>(d)[j] =
          make_ushort4(f2bf(v.x), f2bf(v.y), f2bf(v.z), f2bf(v.w));
    } else {
      j = i - 4194304;                 // float4 index into wcat [1024][128]
      int row = j >> 7, c4 = j & 127;
      int g = row >> 6, q = row & 63;
      const float* src = (q < 32) ? (wz + (size_t)(g * 32 + q) * 512)
                                  : (wh + (size_t)(g * 32 + q - 32) * 512);
      float4 v = reinterpret_cast<const float4*>(src)[c4];
      reinterpret_cast<ushort4*>(wcat)[j] =
          make_ushort4(f2bf(v.x), f2bf(v.y), f2bf(v.z), f2bf(v.w));
    }
  }
}

// ---------------- K1: 8-phase 256^2 GEMM + gate + chunk summaries ----------
// grid 512 (XCD-chunked bijective): tile=(bid&7)*64+(bid>>3); mt=tile>>2 (128),
// nt=tile&3 (4). 8 waves 2Mx4N: wave = 128 rows x 64 cols.
// LDS 128K: buf0A[0,32K) buf0B[32K,64K) buf1A[64K,96K) buf1B[96K,128K);
// tile = [256 rows][64 bf16 = 128B rows, 8 slots], swizzle slot ^= row&7.
__global__ __launch_bounds__(512, 2) void gemm_gate(
    const ushort* __restrict__ xb,    // [32768,512] bf16
    const ushort* __restrict__ wcat,  // [1024,512] bf16 interleaved
    const float* __restrict__ b_z,
    const float* __restrict__ b_h,
    uint* __restrict__ ab,            // [32768,512] packed (a,b) bf16
    float2* __restrict__ ABc)         // [8,512,128] chunk summaries (b,h,c)
{
  __shared__ __align__(16) char smem[131072];

  const int t  = threadIdx.x;
  const int w  = t >> 6;              // wave 0..7
  const int l  = t & 63;
  const int lm = l & 15;
  const int lk = l >> 4;
  const int wm = w >> 2;              // 0..1  (row half)
  const int wn = w & 3;               // 0..3  (64-col group)

  const int bid  = blockIdx.x;
  const int tile = (bid & 7) * 64 + (bid >> 3);   // bijective, 512 % 8 == 0
  const int mt = tile >> 2;           // 0..127
  const int nt = tile & 3;            // 0..3
  const int m0 = mt * 256;
  const int n0 = nt * 256;            // within 1024-wide Wcat rows

  const int sr8 = l >> 3;             // 0..7 (staging row within wave)
  const int gs  = (l & 7) ^ sr8;      // swizzled 16B slot on the GLOBAL side

  enum { B0A = 0, B0B = 32768, B1A = 65536, B1B = 98304 };

  f32x4 acc[8][4];
  #pragma unroll
  for (int m = 0; m < 8; ++m)
    #pragma unroll
    for (int nf = 0; nf < 4; ++nf)
      acc[m][nf] = (f32x4){0.f, 0.f, 0.f, 0.f};

  // stage one half-tile (128 rows) = 2 x gload_lds(16B) per thread
  auto stageA = [&](int region, int kt, int half) {
    #pragma unroll
    for (int j = 0; j < 2; ++j) {
      int row = half * 128 + j * 64 + w * 8 + sr8;
      gload_lds16(xb + (size_t)(m0 + row) * 512 + kt * 64 + gs * 8,
                  smem + region + (half * 128 + j * 64) * 128 + w * 1024);
    }
  };
  auto stageB = [&](int region, int kt, int half) {
    #pragma unroll
    for (int j = 0; j < 2; ++j) {
      int row = half * 128 + j * 64 + w * 8 + sr8;
      gload_lds16(wcat + (size_t)(n0 + row) * 512 + kt * 64 + gs * 8,
                  smem + region + (half * 128 + j * 64) * 128 + w * 1024);
    }
  };

  short8 aF[2][2], bB[4][2];          // A per-phase, B per-K-tile (held 4 ph)

#define RD_A(BUFA, MQ)                                                        \
  _Pragma("unroll") for (int mm = 0; mm < 2; ++mm)                            \
  _Pragma("unroll") for (int ks = 0; ks < 2; ++ks) {                          \
    int row = wm * 128 + (2 * (MQ) + mm) * 16 + lm;                           \
    aF[mm][ks] = *(const short8*)(smem + (BUFA) + row * 128 +                 \
                                  (((ks * 4 + lk) ^ (lm & 7)) << 4));         \
  }

#define RD_B(BUFB)                                                            \
  _Pragma("unroll") for (int nf = 0; nf < 4; ++nf)                            \
  _Pragma("unroll") for (int ks = 0; ks < 2; ++ks) {                          \
    int row = wn * 64 + nf * 16 + lm;                                         \
    bB[nf][ks] = *(const short8*)(smem + (BUFB) + row * 128 +                 \
                                  (((ks * 4 + lk) ^ (lm & 7)) << 4));         \
  }

#define PHASE(BUFA, BUFB, MQ, READB, STAGE, VMN)                              \
  {                                                                           \
    if (READB) { RD_B(BUFB); }                                                \
    RD_A(BUFA, MQ);                                                           \
    STAGE;                                                                    \
    if ((VMN) == 4)      asm volatile("s_waitcnt vmcnt(4)" ::: "memory");     \
    else if ((VMN) == 0) asm volatile("s_waitcnt vmcnt(0)" ::: "memory");     \
    __builtin_amdgcn_s_barrier();                                             \
    asm volatile("s_waitcnt lgkmcnt(0)" ::: "memory");                        \
    __builtin_amdgcn_sched_barrier(0);                                        \
    __builtin_amdgcn_s_setprio(1);                                            \
    _Pragma("unroll") for (int ks = 0; ks < 2; ++ks)                          \
    _Pragma("unroll") for (int nf = 0; nf < 4; ++nf) {                        \
      acc[2 * (MQ)][nf]     = __builtin_amdgcn_mfma_f32_16x16x32_bf16(        \
          aF[0][ks], bB[nf][ks], acc[2 * (MQ)][nf], 0, 0, 0);                 \
      acc[2 * (MQ) + 1][nf] = __builtin_amdgcn_mfma_f32_16x16x32_bf16(        \
          aF[1][ks], bB[nf][ks], acc[2 * (MQ) + 1][nf], 0, 0, 0);             \
    }                                                                         \
    __builtin_amdgcn_s_setprio(0);                                            \
    __builtin_amdgcn_s_barrier();                                             \
  }

  // prologue: A(0),B(0) -> buf0; B(1) -> buf1B; wait all but B(1)
  stageA(B0A, 0, 0); stageA(B0A, 0, 1);
  stageB(B0B, 0, 0); stageB(B0B, 0, 1);
  stageB(B1B, 1, 0); stageB(B1B, 1, 1);
  asm volatile("s_waitcnt vmcnt(4)" ::: "memory");
  __builtin_amdgcn_s_barrier();

  // K = 512 -> 8 K-tiles of 64 -> 4 iters x (even ktile buf0, odd ktile buf1)
  #pragma unroll
  for (int it = 0; it < 4; ++it) {
    const int ko = 2 * it + 1, ke2 = 2 * it + 2, ko2 = 2 * it + 3;
    PHASE(B0A, B0B, 0, true,  { stageA(B1A, ko, 0); },               -1)
    PHASE(B0A, B0B, 1, false, { stageA(B1A, ko, 1); },               -1)
    PHASE(B0A, B0B, 2, false, { if (it < 3) stageB(B0B, ke2, 0); },  -1)
    PHASE(B0A, B0B, 3, false, { if (it < 3) stageB(B0B, ke2, 1); },  (it < 3) ? 4 : 0)
    PHASE(B1A, B1B, 0, true,  { if (it < 3) stageA(B0A, ke2, 0); },  -1)
    PHASE(B1A, B1B, 1, false, { if (it < 3) stageA(B0A, ke2, 1); },  -1)
    PHASE(B1A, B1B, 2, false, { if (it < 3) stageB(B1B, ko2, 0); },  -1)
    PHASE(B1A, B1B, 3, false, { if (it < 3) stageB(B1B, ko2, 1); },  (it < 3) ? 4 : 0)
  }
#undef PHASE
#undef RD_A
#undef RD_B

  // ---- gate epilogue + fused chunk summaries ----
  // C frag layout (16x16): col = lm, row = lk*4 + j. Wave cols = one 64-col
  // group g = nt*4 + wn: nf 0,1 = z of h-channels g*32+{0..31}; nf 2,3 = h~.
  const int g    = nt * 4 + wn;
  const int bidx = mt >> 4;                         // batch
  #pragma unroll
  for (int gp = 0; gp < 2; ++gp) {
    const int h = g * 32 + gp * 16 + lm;
    const float bz = b_z[h], bh = b_h[h];
    #pragma unroll
    for (int cb = 0; cb < 4; ++cb) {                // chunk = 32 rows = 2 frags
      float cA = 1.f, cB = 0.f;
      #pragma unroll
      for (int mm = 0; mm < 2; ++mm) {
        const int m = 2 * cb + mm;
        float sA = 1.f, sB = 0.f;
        #pragma unroll
        for (int j = 0; j < 4; ++j) {
          float uz = acc[m][gp][j] + bz;
          float uh = acc[m][gp + 2][j] + bh;
          float z  = 1.f / (1.f + __expf(-uz));
          float a  = 1.f - z;
          float bb = z * uh;
          size_t grow = (size_t)(m0 + wm * 128 + m * 16 + lk * 4 + j);
          ab[grow * 512 + h] = (uint)f2bf(a) | ((uint)f2bf(bb) << 16);
          sA = a * sA;
          sB = a * sB + bb;                         // j asc = time asc
        }
        float Ag = 1.f, Bg = 0.f;
        #pragma unroll
        for (int q = 0; q < 4; ++q) {               // lk-segments, time order
          float Aq = __shfl(sA, q * 16 + lm);
          float Bq = __shfl(sB, q * 16 + lm);
          Ag = Aq * Ag;
          Bg = Aq * Bg + Bq;
        }
        cB = Ag * cB + Bg;                          // mm asc = time asc
        cA = Ag * cA;
      }
      if (lk == 0) {
        int c = (mt & 15) * 8 + wm * 4 + cb;        // chunk within batch
        ABc[((size_t)bidx * 512 + h) * 128 + c] = make_float2(cA, cB);
      }
    }
  }
}

// ---------------- K3: wave-parallel scan over chunk summaries ----------------
__global__ __launch_bounds__(256) void chunk_scan(
    const float2* __restrict__ ABc,   // [8,512,128]
    const float* __restrict__ h0,
    float* __restrict__ Hinit)        // [8,128,512]
{
  __shared__ float sm[128][4];
  const int w = threadIdx.x >> 6, l = threadIdx.x & 63;
  const int b   = blockIdx.x >> 7;
  const int h0g = (blockIdx.x & 127) * 4;
  const int h   = h0g + w;

  const float2* base = ABc + ((size_t)b * 512 + h) * 128;
  float2 s1 = base[l];
  float2 s2 = base[64 + l];

  float A1 = s1.x, B1 = s1.y;
  #pragma unroll
  for (int d = 1; d < 64; d <<= 1) {
    float uA = __shfl_up(A1, d);
    float uB = __shfl_up(B1, d);
    if (l >= d) { B1 = A1 * uB + B1; A1 = A1 * uA; }
  }
  float A2 = s2.x, B2 = s2.y;
  #pragma unroll
  for (int d = 1; d < 64; d <<= 1) {
    float uA = __shfl_up(A2, d);
    float uB = __shfl_up(B2, d);
    if (l >= d) { B2 = A2 * uB + B2; A2 = A2 * uA; }
  }
  float PA = __shfl(A1, 63), PB = __shfl(B1, 63);   // prefix of chunks 0..63
  float FA = A2 * PA;
  float FB = A2 * PB + B2;

  float e1A = __shfl_up(A1, 1), e1B = __shfl_up(B1, 1);
  if (l == 0) { e1A = 1.f; e1B = 0.f; }
  float e2A = __shfl_up(FA, 1), e2B = __shfl_up(FB, 1);
  if (l == 0) { e2A = PA; e2B = PB; }

  float h0v = h0[b * 512 + h];
  sm[l][w]      = e1A * h0v + e1B;
  sm[64 + l][w] = e2A * h0v + e2B;
  __syncthreads();

  const int tt = threadIdx.x;
  if (tt < 128) {
    float4 v = *(const float4*)sm[tt];
    *(float4*)(Hinit + ((size_t)b * 128 + tt) * 512 + h0g) = v;
  }
}

// ---------------- K4: replay each chunk from Hinit, write out ----------------
__global__ __launch_bounds__(256) void scan_write(
    const uint* __restrict__ ab,
    const float* __restrict__ Hinit,
    float* __restrict__ out)
{
  int tid = blockIdx.x * 256 + threadIdx.x;   // 131072
  int cg = tid & 127;            // h-group: h = cg*4 ..
  int c  = (tid >> 7) & 127;
  int b  = tid >> 14;
  const uint4* p = reinterpret_cast<const uint4*>(ab + ((size_t)(b * 4096 + c * 32)) * 512) + cg;
  float4 hv = *reinterpret_cast<const float4*>(Hinit + ((size_t)b * 128 + c) * 512 + cg * 4);
  float4* po = reinterpret_cast<float4*>(out + ((size_t)(b * 4096 + c * 32)) * 512) + cg;
  #pragma unroll 4
  for (int t = 0; t < 32; ++t) {
    uint4 u = p[(size_t)t * 128];
    hv.x = __uint_as_float(u.x << 16) * hv.x + __uint_as_float(u.x & 0xffff0000u);
    hv.y = __uint_as_float(u.y << 16) * hv.y + __uint_as_float(u.y & 0xffff0000u);
    hv.z = __uint_as_float(u.z << 16) * hv.z + __uint_as_float(u.z & 0xffff0000u);
    hv.w = __uint_as_float(u.w << 16) * hv.w + __uint_as_float(u.w & 0xffff0000u);
    po[(size_t)t * 128] = hv;
  }
}

extern "C" void kernel_launch(void* const* d_in, const int* in_sizes, int n_in,
                              void* d_out, int out_size, void* d_ws, size_t ws_size,
                              hipStream_t stream) {
  const float* x   = (const float*)d_in[0];
  const float* h0  = (const float*)d_in[1];
  const float* W_z = (const float*)d_in[2];
  const float* b_z = (const float*)d_in[3];
  const float* W_h = (const float*)d_in[4];
  const float* b_h = (const float*)d_in[5];
  float* out = (float*)d_out;

  char* ws = (char*)d_ws;
  ushort* xb    = (ushort*)(ws);                  // 33,554,432 B
  ushort* wcat  = (ushort*)(ws + 33554432);       //  1,048,576 B [1024,512]
  uint*   ab    = (uint*)  (ws + 34603008);       // 67,108,864 B
  float2* ABc   = (float2*)(ws + 101711872);      //  4,194,304 B  [8,512,128]
  float*  Hinit = (float*) (ws + 105906176);      //  2,097,152 B  [8,128,512]

  cvt_all<<<2048, 256, 0, stream>>>(x, W_z, W_h, xb, wcat);
  gemm_gate<<<512, 512, 0, stream>>>(xb, wcat, b_z, b_h, ab, ABc);
  chunk_scan<<<1024, 256, 0, stream>>>(ABc, h0, Hinit);
  scan_write<<<512, 256, 0, stream>>>(ab, Hinit, out);
}